// Round 5
// baseline (126.819 us; speedup 1.0000x reference)
//
#include <hip/hip_runtime.h>
#include <hip/hip_bf16.h>

typedef __attribute__((ext_vector_type(8))) short short8v;
typedef __attribute__((ext_vector_type(4))) float f32x4;

#define H_  128
#define W_  128
#define C_  256
#define HW_ 16384

#define MFMA32(a, b, c) __builtin_amdgcn_mfma_f32_16x16x32_bf16(a, b, c, 0, 0, 0)

__device__ __forceinline__ short bf16b(float f) {
    unsigned u = __float_as_uint(f);
    u += 0x7fffu + ((u >> 16) & 1u);   // round-to-nearest-even
    return (short)(u >> 16);
}

// 256 threads = 4 waves. Tile: 4h x 16w pixels, all 81 displacements.
// Wave w owns out row h0+w. K pipelined in 32-channel chunks, ping-pong LDS.
// acc[9][2] = 72 VGPR/thread -> ~90 regs headroom at 2 waves/SIMD, and
// 2 blocks/CU co-resident (LDS ~51KB) -> decoupled barrier domains.
// NOTE: every index into acc[][] must be compile-time constant (round-3 lesson:
// one runtime index demotes the array to scratch: 1.37GB spill writes, 379us).
__global__ __launch_bounds__(256, 2)
void corr_kernel(const float* __restrict__ in1, const float* __restrict__ in2,
                 float* __restrict__ out)
{
    __shared__ short lds2[2][12 * 4 * 32 * 8];   // 2 x 24 KiB ping-pong
    __shared__ float ldso[9 * 65 + 7];           // epilogue band->coalesced staging

    const int tid  = threadIdx.x;
    const int lane = tid & 63;
    const int wid  = tid >> 6;        // 0..3 (= output row within tile)
    const int m    = lane & 15;       // M row / N col in 16x16 tile
    const int g    = lane >> 4;       // k-octet 0..3 (8 k's each, K=32)

    // 2048 blocks, bijective XCD swizzle (2048 % 8 == 0): each XCD gets one image;
    // consecutive bids on an XCD walk w-tiles then h-tiles (halo L2 locality).
    int bid = blockIdx.x;
    int swz = (bid & 7) * 256 + (bid >> 3);
    int n   = swz >> 8;               // 0..7
    int h0  = ((swz >> 3) & 31) << 2; // 0,4,...,124
    int w0  = (swz & 7) << 4;         // 0,16,...,112

    const float* in1n = in1 + (size_t)n * (C_ * HW_);
    const float* in2n = in2 + (size_t)n * (C_ * HW_);

    // ---- chunk-invariant stage geometry: unit u = (r*4+j)*24 + c, 1152 units ----
    // r 0..11 covers in2 rows h0-4 .. h0+7 (wave w, dy -> r = w+dy in 0..11).
    int  lwoff[5]; long gbase[5]; bool act[5], inb[5];
#pragma unroll
    for (int s = 0; s < 5; ++s) {
        int u  = tid + s * 256;
        act[s] = (u < 1152);
        int c  = u % 24;
        int rj = u / 24;              // 0..47
        int j  = rj & 3;
        int r  = rj >> 2;             // 0..11
        int row = h0 - 4 + r;
        int col = w0 - 4 + c;
        inb[s] = act[s] && ((unsigned)row < 128u) && ((unsigned)col < 128u);
        gbase[s] = inb[s] ? ((long)(j * 8) * HW_ + (long)row * W_ + col) : 0;
        lwoff[s] = ((r * 4 + j) * 32 + c) * 8;
    }
    const long abase = (long)(8 * g) * HW_ + (long)(h0 + wid) * W_ + (w0 + m);

    // ---- zero both LDS buffers (cols 24..31 must read as 0), matched store type ----
    {
        short8v z = (short8v)0;
        short8v* zp = (short8v*)&lds2[0][0];
#pragma unroll
        for (int i = 0; i < 12; ++i) zp[tid + i * 256] = z;
    }
    __syncthreads();
    __builtin_amdgcn_sched_barrier(0);

    f32x4 acc[9][2];
#pragma unroll
    for (int d = 0; d < 9; ++d)
#pragma unroll
        for (int t = 0; t < 2; ++t)
            acc[d][t] = (f32x4){0.f, 0.f, 0.f, 0.f};

    // ---- prologue: stage chunk 0 into buf 0 ----
    {
        float sf[5][8];
#pragma unroll
        for (int s = 0; s < 5; ++s)
            if (act[s])
#pragma unroll
                for (int i = 0; i < 8; ++i) {
                    float v = in2n[gbase[s] + (long)i * HW_];
                    sf[s][i] = inb[s] ? v : 0.f;
                }
#pragma unroll
        for (int s = 0; s < 5; ++s)
            if (act[s]) {
                short8v v8;
#pragma unroll
                for (int i = 0; i < 8; ++i) v8[i] = bf16b(sf[s][i]);
                *(short8v*)&lds2[0][lwoff[s]] = v8;
            }
    }

    // ---- main loop: 8 chunks of 32 channels, ping-pong; stage t+1 overlaps MFMA t ----
#pragma unroll 1
    for (int t = 0; t < 8; ++t) {
        __syncthreads();
        __builtin_amdgcn_sched_barrier(0);
        const int rb = t & 1;

        // A-frags for chunk t (read-once): channel 32t + 8g + i, row h0+wid
        float af[8];
#pragma unroll
        for (int i = 0; i < 8; ++i)
            af[i] = in1n[abase + (long)(32 * t + i) * HW_];

        // stage loads for chunk t+1 (issue before MFMA; overlap)
        float sf[5][8];
        if (t < 7) {
            const long koff = (long)((t + 1) * 32) * HW_;
#pragma unroll
            for (int s = 0; s < 5; ++s)
                if (act[s])
#pragma unroll
                    for (int i = 0; i < 8; ++i) {
                        float v = in2n[gbase[s] + koff + (long)i * HW_];
                        sf[s][i] = inb[s] ? v : 0.f;
                    }
        }

        short8v a8;
#pragma unroll
        for (int i = 0; i < 8; ++i) a8[i] = bf16b(af[i]);

        // MFMA from buf rb: wave wid, dy -> LDS row r = wid+dy
        const short* lb = &lds2[rb][0];
#pragma unroll
        for (int dy = 0; dy < 9; ++dy) {
            int ro = ((wid + dy) * 4 + g) * 256;     // *32 cols *8 k (shorts)
#pragma unroll
            for (int nt = 0; nt < 2; ++nt) {
                short8v b = *(const short8v*)&lb[ro + (nt * 16 + m) * 8];
                acc[dy][nt] = MFMA32(a8, b, acc[dy][nt]);
            }
        }

        // write staged chunk t+1 into the other buffer
        if (t < 7) {
#pragma unroll
            for (int s = 0; s < 5; ++s)
                if (act[s]) {
                    short8v v8;
#pragma unroll
                    for (int i = 0; i < 8; ++i) v8[i] = bf16b(sf[s][i]);
                    *(short8v*)&lds2[rb ^ 1][lwoff[s]] = v8;
                }
        }
    }

    // ---- epilogue: band -> ldso (stride 65) -> coalesced 64B stores ----
    // FULLY unrolled over dy: acc indices stay compile-time constants.
    const size_t outb = (size_t)n * 81 * HW_;
#pragma unroll
    for (int dy = 0; dy < 9; ++dy) {
        __syncthreads();
        __builtin_amdgcn_sched_barrier(0);
#pragma unroll
        for (int nt = 0; nt < 2; ++nt) {
#pragma unroll
            for (int i = 0; i < 4; ++i) {
                int mm = 4 * g + i;              // D row = pixel w offset
                int dx = nt * 16 + m - mm;       // D col = mm + dx
                if (dx >= 0 && dx < 9)
                    ldso[dx * 65 + wid * 16 + mm] = acc[dy][nt][i];
            }
        }
        __syncthreads();
        __builtin_amdgcn_sched_barrier(0);
#pragma unroll
        for (int e = 0; e < 3; ++e) {
            int t = tid + e * 256;
            if (t < 576) {
                int dx  = t >> 6;
                int rem = t & 63;                // row*16 + w
                out[outb + (size_t)(dy * 9 + dx) * HW_ +
                    (size_t)(h0 + (rem >> 4)) * W_ + (w0 + (rem & 15))] = ldso[dx * 65 + rem];
            }
        }
    }
}

extern "C" void kernel_launch(void* const* d_in, const int* in_sizes, int n_in,
                              void* d_out, int out_size, void* d_ws, size_t ws_size,
                              hipStream_t stream) {
    const float* in1 = (const float*)d_in[0];
    const float* in2 = (const float*)d_in[1];
    float* out = (float*)d_out;
    corr_kernel<<<dim3(2048), dim3(256), 0, stream>>>(in1, in2, out);
}

// Round 6
// 98.686 us; speedup vs baseline: 1.2851x; 1.2851x over previous
//
#include <hip/hip_runtime.h>
#include <hip/hip_bf16.h>
#include <limits.h>

typedef __attribute__((ext_vector_type(8))) short short8v;
typedef __attribute__((ext_vector_type(4))) short short4v;
typedef __attribute__((ext_vector_type(4))) float f32x4;

#define H_  128
#define W_  128
#define C_  256
#define HW_ 16384

#define MFMA32(a, b, c) __builtin_amdgcn_mfma_f32_16x16x32_bf16(a, b, c, 0, 0, 0)

__device__ __forceinline__ short bf16b(float f) {
    unsigned u = __float_as_uint(f);
    u += 0x7fffu + ((u >> 16) & 1u);   // round-to-nearest-even
    return (short)(u >> 16);
}

// 512 threads = 8 waves. Tile: 16h x 16w pixels, all 81 displacements.
// Wave w owns out rows {2w, 2w+1}. K in 32-channel chunks, ping-pong LDS.
// in2 staged with float4 col-loads (9 VMEM/thread/chunk vs 40 scalar) and
// transposed to k-minor LDS [r][j][col][8k] via 4x ds_write_b16 per unit.
// B-frag reads dedup'd over rr = rs+dy (20 instead of 36 ds_read_b128/wave).
// NOTE: every index into acc[][][] must be compile-time constant (round-3
// lesson: one runtime index demotes acc to scratch -> 1.37GB spill writes).
__global__ __launch_bounds__(512, 2)
void corr_kernel(const float* __restrict__ in1, const float* __restrict__ in2,
                 float* __restrict__ out)
{
    __shared__ short lds2[2][24 * 4 * 32 * 8];   // 2 x 48 KiB ping-pong
    __shared__ float ldso[9 * 257];              // epilogue band->coalesced staging

    const int tid  = threadIdx.x;
    const int lane = tid & 63;
    const int wid  = tid >> 6;        // 0..7
    const int m    = lane & 15;       // M row / N col in 16x16 tile
    const int g    = lane >> 4;       // k-octet 0..3 (8 k's each, K=32)

    int bid = blockIdx.x;
    int swz = (bid & 7) * 64 + (bid >> 3);       // bijective XCD swizzle; 1 image/XCD
    int n   = swz >> 6;
    int h0  = ((swz >> 3) & 7) << 4;
    int w0  = (swz & 7) << 4;

    const float* in1n = in1 + (size_t)n * (C_ * HW_);
    const float* in2n = in2 + (size_t)n * (C_ * HW_);

    // ---- chunk-invariant stage geometry ----
    // f4-unit u: q=col-group(0..5, c0=4q), i=k-in-octet(0..7), j=k-octet(0..3), r=row(0..23)
    // 24*4*8*6 = 4608 units = 9 * 512 exactly.
    int lwoff[9]; int gofs[9];
#pragma unroll
    for (int s = 0; s < 9; ++s) {
        int u    = tid + s * 512;
        int q    = u % 6;
        int rest = u / 6;             // 0..767
        int i    = rest & 7;
        int rj   = rest >> 3;         // 0..95
        int j    = rj & 3;
        int r    = rj >> 2;           // 0..23
        int row  = h0 - 4 + r;
        int col0 = w0 - 4 + 4 * q;
        bool inb = ((unsigned)row < 128u) && ((unsigned)col0 < 125u);
        gofs[s]  = inb ? ((j * 8 + i) * HW_ + row * W_ + col0) : INT_MIN;
        lwoff[s] = ((r * 4 + j) * 32 + 4 * q) * 8 + i;
    }
    const int abase = (8 * g) * HW_ + (h0 + 2 * wid) * W_ + (w0 + m);

    // ---- zero both LDS buffers (cols 24..31 must read as 0) ----
    {
        short8v z = (short8v)0;
        short8v* zp = (short8v*)&lds2[0][0];
#pragma unroll
        for (int i = 0; i < 12; ++i) zp[tid + i * 512] = z;
    }
    __syncthreads();
    __builtin_amdgcn_sched_barrier(0);

    f32x4 acc[2][9][2];
#pragma unroll
    for (int a = 0; a < 2; ++a)
#pragma unroll
        for (int d = 0; d < 9; ++d)
#pragma unroll
            for (int t = 0; t < 2; ++t)
                acc[a][d][t] = (f32x4){0.f, 0.f, 0.f, 0.f};

    // ---- prologue: stage chunk 0 into buf 0 ----
    {
        f32x4 sv[9];
#pragma unroll
        for (int s = 0; s < 9; ++s) {
            f32x4 v = (f32x4){0.f, 0.f, 0.f, 0.f};
            if (gofs[s] != INT_MIN) v = *(const f32x4*)(in2n + gofs[s]);
            sv[s] = v;
        }
#pragma unroll
        for (int s = 0; s < 9; ++s) {
            short* p = &lds2[0][lwoff[s]];
#pragma unroll
            for (int d = 0; d < 4; ++d) p[8 * d] = bf16b(sv[s][d]);
        }
    }

    // ---- main loop: 8 chunks of 32 channels, ping-pong; stage t+1 overlaps MFMA t ----
#pragma unroll 1
    for (int t = 0; t < 8; ++t) {
        __syncthreads();
        __builtin_amdgcn_sched_barrier(0);
        const int rb = t & 1;

        // A loads for chunk t (issued first so their vmcnt drains first)
        float af[2][8];
#pragma unroll
        for (int rs = 0; rs < 2; ++rs)
#pragma unroll
            for (int i = 0; i < 8; ++i)
                af[rs][i] = in1n[abase + (32 * t + i) * HW_ + rs * W_];

        // in2 float4 loads for chunk t+1 (latency hidden under MFMA below)
        f32x4 sv[9];
        if (t < 7) {
            const int koff = (t + 1) * 32 * HW_;
#pragma unroll
            for (int s = 0; s < 9; ++s) {
                f32x4 v = (f32x4){0.f, 0.f, 0.f, 0.f};
                if (gofs[s] != INT_MIN) v = *(const f32x4*)(in2n + gofs[s] + koff);
                sv[s] = v;
            }
        }

        short8v a8[2];
#pragma unroll
        for (int rs = 0; rs < 2; ++rs)
#pragma unroll
            for (int i = 0; i < 8; ++i) a8[rs][i] = bf16b(af[rs][i]);

        // MFMA, dedup'd over rr = rs+dy: B row 2wid+rr read once, used by up to 2 acc rows
        const short* lb = &lds2[rb][0];
#pragma unroll
        for (int rr = 0; rr < 10; ++rr) {
            int ro = (((2 * wid + rr) * 4 + g) * 32) * 8;
            short8v b0 = *(const short8v*)&lb[ro + m * 8];
            short8v b1 = *(const short8v*)&lb[ro + (16 + m) * 8];
            if (rr <= 8) {
                acc[0][rr][0] = MFMA32(a8[0], b0, acc[0][rr][0]);
                acc[0][rr][1] = MFMA32(a8[0], b1, acc[0][rr][1]);
            }
            if (rr >= 1) {
                acc[1][rr - 1][0] = MFMA32(a8[1], b0, acc[1][rr - 1][0]);
                acc[1][rr - 1][1] = MFMA32(a8[1], b1, acc[1][rr - 1][1]);
            }
        }

        // transpose-scatter staged chunk t+1 into the other buffer (4 x b16 per unit)
        if (t < 7) {
#pragma unroll
            for (int s = 0; s < 9; ++s) {
                short* p = &lds2[rb ^ 1][lwoff[s]];
#pragma unroll
                for (int d = 0; d < 4; ++d) p[8 * d] = bf16b(sv[s][d]);
            }
        }
    }

    // ---- epilogue: band -> ldso (stride 257) -> coalesced 64B stores ----
    // FULLY unrolled over dy: acc indices stay compile-time constants.
    const size_t outb = (size_t)n * 81 * HW_;
#pragma unroll
    for (int dy = 0; dy < 9; ++dy) {
        __syncthreads();
        __builtin_amdgcn_sched_barrier(0);
#pragma unroll
        for (int rs = 0; rs < 2; ++rs) {
            int hl = 2 * wid + rs;
#pragma unroll
            for (int nt = 0; nt < 2; ++nt) {
#pragma unroll
                for (int i = 0; i < 4; ++i) {
                    int mm = 4 * g + i;              // D row = pixel w offset
                    int dx = nt * 16 + m - mm;       // D col = mm + dx
                    if (dx >= 0 && dx < 9)
                        ldso[dx * 257 + hl * 16 + mm] = acc[rs][dy][nt][i];
                }
            }
        }
        __syncthreads();
        __builtin_amdgcn_sched_barrier(0);
#pragma unroll
        for (int e = 0; e < 5; ++e) {
            int t = tid + e * 512;
            if (t < 2304) {
                int dx  = t >> 8;
                int rem = t & 255;                   // hl*16 + w
                out[outb + (size_t)(dy * 9 + dx) * HW_ +
                    (size_t)(h0 + (rem >> 4)) * W_ + (w0 + (rem & 15))] = ldso[dx * 257 + rem];
            }
        }
    }
}

extern "C" void kernel_launch(void* const* d_in, const int* in_sizes, int n_in,
                              void* d_out, int out_size, void* d_ws, size_t ws_size,
                              hipStream_t stream) {
    const float* in1 = (const float*)d_in[0];
    const float* in2 = (const float*)d_in[1];
    float* out = (float*)d_out;
    corr_kernel<<<dim3(512), dim3(512), 0, stream>>>(in1, in2, out);
}

// Round 7
// 98.242 us; speedup vs baseline: 1.2909x; 1.0045x over previous
//
#include <hip/hip_runtime.h>
#include <limits.h>

typedef __attribute__((ext_vector_type(8))) short short8v;
typedef __attribute__((ext_vector_type(4))) float f32x4;

#define H_  128
#define W_  128
#define C_  256
#define HW_ 16384

#define MFMA32(a, b, c) __builtin_amdgcn_mfma_f32_16x16x32_bf16(a, b, c, 0, 0, 0)

__device__ __forceinline__ short bf16b(float f) {
    unsigned u = __float_as_uint(f);
    u += 0x7fffu + ((u >> 16) & 1u);   // RNE
    return (short)(u >> 16);
}
__device__ __forceinline__ unsigned bf16pk(float lo, float hi) {
    unsigned ul = __float_as_uint(lo);
    ul += 0x7fffu + ((ul >> 16) & 1u);
    unsigned uh = __float_as_uint(hi);
    uh += 0x7fffu + ((uh >> 16) & 1u);
    return (ul >> 16) | (uh & 0xffff0000u);
}

// 512 threads = 8 waves. Tile: 16h x 16w pixels, all 81 displacements.
// K in 32-channel chunks; TRIPLE-buffered LDS: loads for chunk t+2 issued at
// iter t, written at iter t+1 -> ds_write never waits on vmcnt, no drain at
// barrier. Staging unit = k-pair: 2x float4 (c=2kp,2kp+1 x 4 cols) -> 4 packed
// dwords at 16B stride (~2-way banks, free). Read layout [r][j][col32][8k]
// unchanged (validated); 20 dedup'd ds_read_b128/wave.
// NOTE: all acc[][][] indices compile-time constant (round-3 lesson: runtime
// index -> scratch demotion, 1.37GB spill writes).
__global__ __launch_bounds__(512, 2)
void corr_kernel(const float* __restrict__ in1, const float* __restrict__ in2,
                 float* __restrict__ out)
{
    // 3 x 48KB in2 buffers; epilogue staging aliases buffer 0 (used after loop).
    __shared__ __attribute__((aligned(16))) unsigned char smem[3 * 49152];
    short*    lds  = (short*)smem;
    unsigned* ldsI = (unsigned*)smem;
    float*    ldso = (float*)smem;

    const int tid  = threadIdx.x;
    const int lane = tid & 63;
    const int wid  = tid >> 6;        // 0..7
    const int m    = lane & 15;       // M row / N col in 16x16 tile
    const int g    = lane >> 4;       // k-octet 0..3

    int bid = blockIdx.x;
    int swz = (bid & 7) * 64 + (bid >> 3);       // bijective XCD swizzle; 1 image/XCD
    int n   = swz >> 6;
    int h0  = ((swz >> 3) & 7) << 4;
    int w0  = (swz & 7) << 4;

    const float* in1n = in1 + (size_t)n * (C_ * HW_);
    const float* in2n = in2 + (size_t)n * (C_ * HW_);

    // ---- chunk-invariant stage geometry: pair-unit u = (r*16+kp)*6 + q ----
    // 24 r x 16 kp x 6 q = 2304 units; unit loads c=2kp,2kp+1 (within chunk),
    // cols 4q..4q+3 of row r; writes 4 dwords (bf16 pairs) at 16B stride.
    int lwdw[5]; int gof0[5];
#pragma unroll
    for (int s = 0; s < 5; ++s) {
        int u    = tid + s * 512;
        bool act = (u < 2304);
        int q    = u % 6;
        int rest = u / 6;             // 0..383
        int kp   = rest & 15;
        int r    = rest >> 4;         // 0..23
        int row  = h0 - 4 + r;
        int col0 = w0 - 4 + 4 * q;
        bool inb = act && ((unsigned)row < 128u) && ((unsigned)col0 < 125u);
        int  cc  = 8 * (kp >> 2) + 2 * (kp & 3);          // channel-in-chunk (even)
        gof0[s]  = inb ? (cc * HW_ + row * W_ + col0) : INT_MIN;
        lwdw[s]  = ((r * 4 + (kp >> 2)) * 32 + 4 * q) * 4 + (kp & 3);
    }
    const int abase = (8 * g) * HW_ + (h0 + 2 * wid) * W_ + (w0 + m);

    // ---- zero all 3 buffers (cols 24..31 junk region must read as 0) ----
    {
        short8v z = (short8v)0;
        short8v* zp = (short8v*)lds;
#pragma unroll
        for (int i = 0; i < 18; ++i) zp[tid + i * 512] = z;
    }

    f32x4 acc[2][9][2];
#pragma unroll
    for (int a = 0; a < 2; ++a)
#pragma unroll
        for (int d = 0; d < 9; ++d)
#pragma unroll
            for (int t = 0; t < 2; ++t)
                acc[a][d][t] = (f32x4){0.f, 0.f, 0.f, 0.f};

    __syncthreads();
    __builtin_amdgcn_sched_barrier(0);

    f32x4 sf[5][2];    // staged in2: [unit][e] (e = channel parity)
    float afn[2][8];   // prefetched A for next-computed chunk

    // ---- prologue ----
    // stage chunk 0 -> buf 0
#pragma unroll
    for (int s = 0; s < 5; ++s)
#pragma unroll
        for (int e = 0; e < 2; ++e) {
            f32x4 v = (f32x4){0.f, 0.f, 0.f, 0.f};
            if (gof0[s] != INT_MIN) v = *(const f32x4*)(in2n + gof0[s] + e * HW_);
            sf[s][e] = v;
        }
#pragma unroll
    for (int s = 0; s < 5; ++s)
        if (tid + s * 512 < 2304) {
#pragma unroll
            for (int d = 0; d < 4; ++d)
                ldsI[lwdw[s] + 4 * d] = bf16pk(sf[s][0][d], sf[s][1][d]);
        }
    // load chunk 1 -> sf
#pragma unroll
    for (int s = 0; s < 5; ++s)
#pragma unroll
        for (int e = 0; e < 2; ++e) {
            f32x4 v = (f32x4){0.f, 0.f, 0.f, 0.f};
            if (gof0[s] != INT_MIN) v = *(const f32x4*)(in2n + gof0[s] + e * HW_ + 32 * HW_);
            sf[s][e] = v;
        }
    // load A chunk 0 -> afn
#pragma unroll
    for (int rs = 0; rs < 2; ++rs)
#pragma unroll
        for (int i = 0; i < 8; ++i)
            afn[rs][i] = in1n[abase + i * HW_ + rs * W_];

    // ---- main loop: 8 chunks; buf[t%3] read, buf[(t+1)%3] written ----
#pragma unroll 1
    for (int t = 0; t < 8; ++t) {
        __syncthreads();
        __builtin_amdgcn_sched_barrier(0);
        const int bcur  = t % 3;
        const int wnext = (t + 1) % 3;

        // A frags for chunk t (loaded >=1 iter ago)
        short8v a8[2];
#pragma unroll
        for (int rs = 0; rs < 2; ++rs)
#pragma unroll
            for (int i = 0; i < 8; ++i) a8[rs][i] = bf16b(afn[rs][i]);

        // write chunk t+1 (loaded last iter; vmcnt long satisfied)
        if (t < 7) {
            unsigned* wp = ldsI + wnext * 12288;
#pragma unroll
            for (int s = 0; s < 5; ++s)
                if (tid + s * 512 < 2304) {
#pragma unroll
                    for (int d = 0; d < 4; ++d)
                        wp[lwdw[s] + 4 * d] = bf16pk(sf[s][0][d], sf[s][1][d]);
                }
        }
        // issue loads for chunk t+2 (consumed next iter)
        if (t < 6) {
            const int koff = (t + 2) * 32 * HW_;
#pragma unroll
            for (int s = 0; s < 5; ++s)
#pragma unroll
                for (int e = 0; e < 2; ++e) {
                    f32x4 v = (f32x4){0.f, 0.f, 0.f, 0.f};
                    if (gof0[s] != INT_MIN) v = *(const f32x4*)(in2n + gof0[s] + e * HW_ + koff);
                    sf[s][e] = v;
                }
        }
        // issue A loads for chunk t+1
        if (t < 7) {
            const int akoff = (t + 1) * 32 * HW_;
#pragma unroll
            for (int rs = 0; rs < 2; ++rs)
#pragma unroll
                for (int i = 0; i < 8; ++i)
                    afn[rs][i] = in1n[abase + (akoff + i * HW_) + rs * W_];
        }

        // MFMA from buf[bcur]; B row rr shared by acc rows (rs=0,dy=rr),(rs=1,dy=rr-1)
        const short* lb = lds + bcur * 24576;
#pragma unroll
        for (int rr = 0; rr < 10; ++rr) {
            int ro = (((2 * wid + rr) * 4 + g) * 32) * 8;
            short8v b0 = *(const short8v*)&lb[ro + m * 8];
            short8v b1 = *(const short8v*)&lb[ro + (16 + m) * 8];
            if (rr <= 8) {
                acc[0][rr][0] = MFMA32(a8[0], b0, acc[0][rr][0]);
                acc[0][rr][1] = MFMA32(a8[0], b1, acc[0][rr][1]);
            }
            if (rr >= 1) {
                acc[1][rr - 1][0] = MFMA32(a8[1], b0, acc[1][rr - 1][0]);
                acc[1][rr - 1][1] = MFMA32(a8[1], b1, acc[1][rr - 1][1]);
            }
        }
    }

    // ---- epilogue: band -> ldso (stride 257, aliases buf0) -> coalesced stores ----
    const size_t outb = (size_t)n * 81 * HW_;
#pragma unroll
    for (int dy = 0; dy < 9; ++dy) {
        __syncthreads();
        __builtin_amdgcn_sched_barrier(0);
#pragma unroll
        for (int rs = 0; rs < 2; ++rs) {
            int hl = 2 * wid + rs;
#pragma unroll
            for (int nt = 0; nt < 2; ++nt) {
#pragma unroll
                for (int i = 0; i < 4; ++i) {
                    int mm = 4 * g + i;              // D row = pixel w offset
                    int dx = nt * 16 + m - mm;       // D col = mm + dx
                    if (dx >= 0 && dx < 9)
                        ldso[dx * 257 + hl * 16 + mm] = acc[rs][dy][nt][i];
                }
            }
        }
        __syncthreads();
        __builtin_amdgcn_sched_barrier(0);
#pragma unroll
        for (int e = 0; e < 5; ++e) {
            int t = tid + e * 512;
            if (t < 2304) {
                int dx  = t >> 8;
                int rem = t & 255;                   // hl*16 + w
                out[outb + (size_t)(dy * 9 + dx) * HW_ +
                    (size_t)(h0 + (rem >> 4)) * W_ + (w0 + (rem & 15))] = ldso[dx * 257 + rem];
            }
        }
    }
}

extern "C" void kernel_launch(void* const* d_in, const int* in_sizes, int n_in,
                              void* d_out, int out_size, void* d_ws, size_t ws_size,
                              hipStream_t stream) {
    const float* in1 = (const float*)d_in[0];
    const float* in2 = (const float*)d_in[1];
    float* out = (float*)d_out;
    corr_kernel<<<dim3(512), dim3(512), 0, stream>>>(in1, in2, out);
}